// Round 1
// baseline (1047.842 us; speedup 1.0000x reference)
//
#include <hip/hip_runtime.h>
#include <hip/hip_bf16.h>
#include <cstddef>

namespace {

constexpr int N = 100000;
constexpr int IN = 256;
constexpr int H = 128;
constexpr int OUT = 16;
constexpr int R = 5;
constexpr int E = 100000;

constexpr int BM = 64;   // rows per block in GEMM
constexpr int KB = 32;   // K chunk staged in LDS

__global__ void zero_f32(float* __restrict__ p, int n) {
  int i = blockIdx.x * 256 + threadIdx.x;
  if (i < n) p[i] = 0.f;
}

__global__ void deg_count(const int* __restrict__ dst, float* __restrict__ deg) {
  int i = blockIdx.x * 256 + threadIdx.x;
  if (i < R * E) atomicAdd(&deg[(i / E) * N + dst[i]], 1.0f);
}

__global__ void inv_deg_k(float* __restrict__ deg) {
  int i = blockIdx.x * 256 + threadIdx.x;
  if (i < R * N) deg[i] = 1.0f / fmaxf(deg[i], 1.0f);
}

// wc[row][b*outw + o] = basis[b][row][o]   (B = 2)
__global__ void build_wc(const float* __restrict__ basis, float* __restrict__ wc,
                         int rows, int outw) {
  int i = blockIdx.x * 256 + threadIdx.x;
  int total = rows * 2 * outw;
  if (i < total) {
    int row = i / (2 * outw);
    int c = i % (2 * outw);
    int b = c / outw;
    int o = c % outw;
    wc[i] = basis[(b * rows + row) * outw + o];
  }
}

// C[M,NOUT] = A[M,K] @ W[K,NOUT] (+bias). fp32, LDS-staged A (transposed, padded).
template <int K, int NOUT, bool BIAS>
__global__ __launch_bounds__(256) void gemm_f32(
    const float* __restrict__ A, const float* __restrict__ W,
    const float* __restrict__ bias, float* __restrict__ C, int M) {
  constexpr int NC = NOUT / 16;       // cols per thread (16 col-groups)
  __shared__ float Alds[KB][BM + 1];  // +1 pad: conflict-free transposed writes
  const int tid = threadIdx.x;
  const int tx = tid & 15;
  const int ty = tid >> 4;
  const int bm = blockIdx.x * BM;

  float acc[4][NC];
#pragma unroll
  for (int i = 0; i < 4; ++i)
#pragma unroll
    for (int j = 0; j < NC; ++j) acc[i][j] = 0.f;

  // cooperative-load mapping: 64 rows x 32 k, 8 elems/thread
  const int linear = tid * 8;
  const int lrow = linear >> 5;        // /KB
  const int lkk = linear & (KB - 1);
  int grow = bm + lrow;
  if (grow >= M) grow = M - 1;         // clamp; results unused
  const float* asrc = A + (size_t)grow * K + lkk;

  for (int kb = 0; kb < K; kb += KB) {
    float4 v0 = *(const float4*)(asrc + kb);
    float4 v1 = *(const float4*)(asrc + kb + 4);
    Alds[lkk + 0][lrow] = v0.x;
    Alds[lkk + 1][lrow] = v0.y;
    Alds[lkk + 2][lrow] = v0.z;
    Alds[lkk + 3][lrow] = v0.w;
    Alds[lkk + 4][lrow] = v1.x;
    Alds[lkk + 5][lrow] = v1.y;
    Alds[lkk + 6][lrow] = v1.z;
    Alds[lkk + 7][lrow] = v1.w;
    __syncthreads();
#pragma unroll 4
    for (int k2 = 0; k2 < KB; ++k2) {
      float a0 = Alds[k2][ty * 4 + 0];
      float a1 = Alds[k2][ty * 4 + 1];
      float a2 = Alds[k2][ty * 4 + 2];
      float a3 = Alds[k2][ty * 4 + 3];
      const float* wp = W + (size_t)(kb + k2) * NOUT + tx * NC;
      float w[NC];
      if constexpr (NC % 4 == 0) {
#pragma unroll
        for (int j = 0; j < NC; j += 4) {
          float4 t = *(const float4*)(wp + j);
          w[j] = t.x; w[j + 1] = t.y; w[j + 2] = t.z; w[j + 3] = t.w;
        }
      } else {
        float2 t = *(const float2*)wp;
        w[0] = t.x; w[1] = t.y;
      }
#pragma unroll
      for (int j = 0; j < NC; ++j) {
        acc[0][j] = fmaf(a0, w[j], acc[0][j]);
        acc[1][j] = fmaf(a1, w[j], acc[1][j]);
        acc[2][j] = fmaf(a2, w[j], acc[2][j]);
        acc[3][j] = fmaf(a3, w[j], acc[3][j]);
      }
    }
    __syncthreads();
  }

#pragma unroll
  for (int i = 0; i < 4; ++i) {
    int grow2 = bm + ty * 4 + i;
    if (grow2 < M) {
      float* crow = C + (size_t)grow2 * NOUT + tx * NC;
#pragma unroll
      for (int j = 0; j < NC; ++j) {
        float v = acc[i][j];
        if constexpr (BIAS) v += bias[tx * NC + j];
        crow[j] = v;
      }
    }
  }
}

__global__ void init_bias(float* __restrict__ C, const float* __restrict__ bias,
                          int n, int mask) {
  int i = blockIdx.x * 256 + threadIdx.x;
  if (i < n) C[i] = bias[i & mask];
}

__global__ void relu_k(float* __restrict__ p, int n) {
  int i = blockIdx.x * 256 + threadIdx.x;
  if (i < n) p[i] = fmaxf(p[i], 0.f);
}

// layer-1 edge scatter: one wave per edge, 128 cols (float2/lane)
__global__ void edge_pass_h(const int* __restrict__ src, const int* __restrict__ dst,
                            const float* __restrict__ coef, const float* __restrict__ invdeg,
                            const float* __restrict__ p, float* __restrict__ acc) {
  int eidx = blockIdx.x * 4 + (threadIdx.x >> 6);
  int lane = threadIdx.x & 63;
  if (eidx >= R * E) return;
  int r = eidx / E;
  int s = src[eidx];
  int d = dst[eidx];
  float id = invdeg[r * N + d];
  float c0 = coef[r * 2 + 0] * id;
  float c1 = coef[r * 2 + 1] * id;
  const float2* prow = (const float2*)(p + (size_t)s * 256);
  float2 a = prow[lane];        // p0 part, cols 2l..2l+1
  float2 b = prow[lane + 64];   // p1 part
  float mx = c0 * a.x + c1 * b.x;
  float my = c0 * a.y + c1 * b.y;
  float* arow = acc + (size_t)d * 128 + lane * 2;
  atomicAdd(arow, mx);
  atomicAdd(arow + 1, my);
}

// layer-2 edge scatter: 16 lanes per edge
__global__ void edge_pass_o(const int* __restrict__ src, const int* __restrict__ dst,
                            const float* __restrict__ coef, const float* __restrict__ invdeg,
                            const float* __restrict__ q, float* __restrict__ out) {
  int t = threadIdx.x;
  int eidx = blockIdx.x * 16 + (t >> 4);
  int k = t & 15;
  if (eidx >= R * E) return;
  int r = eidx / E;
  int s = src[eidx];
  int d = dst[eidx];
  float id = invdeg[r * N + d];
  float c0 = coef[r * 2 + 0] * id;
  float c1 = coef[r * 2 + 1] * id;
  float v = c0 * q[(size_t)s * 32 + k] + c1 * q[(size_t)s * 32 + 16 + k];
  atomicAdd(&out[(size_t)d * 16 + k], v);
}

}  // namespace

extern "C" void kernel_launch(void* const* d_in, const int* in_sizes, int n_in,
                              void* d_out, int out_size, void* d_ws, size_t ws_size,
                              hipStream_t stream) {
  const float* x       = (const float*)d_in[0];
  const int*   src     = (const int*)d_in[1];
  const int*   dst     = (const int*)d_in[2];
  const float* w_embed = (const float*)d_in[3];
  const float* b_embed = (const float*)d_in[4];
  const float* basis1  = (const float*)d_in[5];
  const float* coef1   = (const float*)d_in[6];
  const float* bias1   = (const float*)d_in[7];
  const float* basis2  = (const float*)d_in[8];
  const float* coef2   = (const float*)d_in[9];
  const float* bias2   = (const float*)d_in[10];
  float* out = (float*)d_out;

  float* ws = (float*)d_ws;
  float* invdeg = ws;                       // R*N          = 500,000
  float* wc1 = invdeg + R * N;              // 128*256      = 32,768
  float* wc2 = wc1 + 128 * 256;             // 128*32       = 4,096
  float* h   = wc2 + 128 * 32;              // N*H          = 12.8M
  float* p   = h + (size_t)N * H;           // N*2H         = 25.6M
  float* acc1 = h;                          // alias: h dead after p is built
  float* q    = p;                          // alias: p dead after edge pass 1

  dim3 b256(256);
  zero_f32<<<(R * N + 255) / 256, b256, 0, stream>>>(invdeg, R * N);
  deg_count<<<(R * E + 255) / 256, b256, 0, stream>>>(dst, invdeg);
  inv_deg_k<<<(R * N + 255) / 256, b256, 0, stream>>>(invdeg);
  build_wc<<<(128 * 256 + 255) / 256, b256, 0, stream>>>(basis1, wc1, 128, 128);
  build_wc<<<(128 * 32 + 255) / 256, b256, 0, stream>>>(basis2, wc2, 128, 16);

  int gblocks = (N + BM - 1) / BM;
  // h = x @ w_embed + b_embed
  gemm_f32<IN, 128, true><<<gblocks, b256, 0, stream>>>(x, w_embed, b_embed, h, N);
  // p = h @ [V1_0 | V1_1]   -> [N, 256]
  gemm_f32<128, 256, false><<<gblocks, b256, 0, stream>>>(h, wc1, nullptr, p, N);
  // acc1 = bias1 (broadcast), then scatter edges
  init_bias<<<(N * H + 255) / 256, b256, 0, stream>>>(acc1, bias1, N * H, H - 1);
  edge_pass_h<<<(R * E) / 4, b256, 0, stream>>>(src, dst, coef1, invdeg, p, acc1);
  relu_k<<<(N * H + 255) / 256, b256, 0, stream>>>(acc1, N * H);
  // q = h2 @ [V2_0 | V2_1]  -> [N, 32]
  gemm_f32<128, 32, false><<<gblocks, b256, 0, stream>>>(acc1, wc2, nullptr, q, N);
  // out = bias2 (broadcast), then scatter edges
  init_bias<<<(N * OUT + 255) / 256, b256, 0, stream>>>(out, bias2, N * OUT, OUT - 1);
  edge_pass_o<<<(R * E) / 16, b256, 0, stream>>>(src, dst, coef2, invdeg, q, out);
}

// Round 2
// 626.290 us; speedup vs baseline: 1.6731x; 1.6731x over previous
//
#include <hip/hip_runtime.h>
#include <hip/hip_bf16.h>
#include <cstddef>

namespace {

constexpr int N = 100000;
constexpr int IN = 256;
constexpr int H = 128;
constexpr int OUT = 16;
constexpr int R = 5;
constexpr int E = 100000;
constexpr int RE = R * E;
constexpr int NB = (N + 255) / 256;  // 391 scan blocks

constexpr int BM = 64;   // rows per block in GEMM
constexpr int KB = 32;   // K chunk staged in LDS

__global__ void deg_count(const int* __restrict__ dst, float* __restrict__ deg,
                          int* __restrict__ degtot) {
  int i = blockIdx.x * 256 + threadIdx.x;
  if (i < RE) {
    int d = dst[i];
    atomicAdd(&deg[(i / E) * N + d], 1.0f);
    atomicAdd(&degtot[d], 1);
  }
}

__global__ void inv_deg_k(float* __restrict__ deg) {
  int i = blockIdx.x * 256 + threadIdx.x;
  if (i < R * N) deg[i] = 1.0f / fmaxf(deg[i], 1.0f);
}

// wc[row][b*outw + o] = basis[b][row][o]   (B = 2)
__global__ void build_wc(const float* __restrict__ basis, float* __restrict__ wc,
                         int rows, int outw) {
  int i = blockIdx.x * 256 + threadIdx.x;
  int total = rows * 2 * outw;
  if (i < total) {
    int row = i / (2 * outw);
    int c = i % (2 * outw);
    int b = c / outw;
    int o = c % outw;
    wc[i] = basis[(b * rows + row) * outw + o];
  }
}

// ---- exclusive prefix scan over degtot (3 kernels) ----
__global__ void scan_blk(const int* __restrict__ in, int* __restrict__ part,
                         int* __restrict__ bsum, int n) {
  __shared__ int tmp[256];
  int tid = threadIdx.x;
  int gid = blockIdx.x * 256 + tid;
  int v = (gid < n) ? in[gid] : 0;
  tmp[tid] = v;
  __syncthreads();
  for (int o = 1; o < 256; o <<= 1) {
    int t = (tid >= o) ? tmp[tid - o] : 0;
    __syncthreads();
    tmp[tid] += t;
    __syncthreads();
  }
  if (gid < n) part[gid] = tmp[tid] - v;  // exclusive
  if (tid == 255) bsum[blockIdx.x] = tmp[255];
}

__global__ void scan_top(const int* __restrict__ bsum, int* __restrict__ bscan, int nb) {
  __shared__ int tmp[512];
  int tid = threadIdx.x;
  int v = (tid < nb) ? bsum[tid] : 0;
  tmp[tid] = v;
  __syncthreads();
  for (int o = 1; o < 512; o <<= 1) {
    int t = (tid >= o) ? tmp[tid - o] : 0;
    __syncthreads();
    tmp[tid] += t;
    __syncthreads();
  }
  if (tid < nb) bscan[tid] = tmp[tid] - v;  // exclusive
}

__global__ void scan_add(int* __restrict__ part, const int* __restrict__ bscan, int n) {
  int gid = blockIdx.x * 256 + threadIdx.x;
  if (gid < n) part[gid] += bscan[gid >> 8];  // part becomes off[]
}

// counting-sort edges into dst-grouped slots; precompute per-edge scalar
// weights (coef[r,b] * invdeg[r][d]) for both layers.
__global__ void fill_csr(const int* __restrict__ src, const int* __restrict__ dst,
                         const float* __restrict__ coef1, const float* __restrict__ coef2,
                         const float* __restrict__ invdeg, const int* __restrict__ off,
                         int* __restrict__ cursor, int* __restrict__ esrc,
                         float2* __restrict__ ecA, float2* __restrict__ ecB) {
  int i = blockIdx.x * 256 + threadIdx.x;
  if (i >= RE) return;
  int r = i / E;
  int d = dst[i];
  int slot = off[d] + atomicAdd(&cursor[d], 1);
  float id = invdeg[r * N + d];
  esrc[slot] = src[i];
  ecA[slot] = make_float2(coef1[2 * r] * id, coef1[2 * r + 1] * id);
  ecB[slot] = make_float2(coef2[2 * r] * id, coef2[2 * r + 1] * id);
}

// C[M,NOUT] = A[M,K] @ W[K,NOUT] (+bias, +relu). fp32, LDS-staged A.
template <int K, int NOUT, bool BIAS, bool RELU>
__global__ __launch_bounds__(256) void gemm_f32(
    const float* __restrict__ A, const float* __restrict__ W,
    const float* __restrict__ bias, float* __restrict__ C, int M) {
  constexpr int NC = NOUT / 16;       // cols per thread (16 col-groups)
  __shared__ float Alds[KB][BM + 1];
  const int tid = threadIdx.x;
  const int tx = tid & 15;
  const int ty = tid >> 4;
  const int bm = blockIdx.x * BM;

  float acc[4][NC];
#pragma unroll
  for (int i = 0; i < 4; ++i)
#pragma unroll
    for (int j = 0; j < NC; ++j) acc[i][j] = 0.f;

  const int linear = tid * 8;
  const int lrow = linear >> 5;
  const int lkk = linear & (KB - 1);
  int grow = bm + lrow;
  if (grow >= M) grow = M - 1;
  const float* asrc = A + (size_t)grow * K + lkk;

  for (int kb = 0; kb < K; kb += KB) {
    float4 v0 = *(const float4*)(asrc + kb);
    float4 v1 = *(const float4*)(asrc + kb + 4);
    Alds[lkk + 0][lrow] = v0.x;
    Alds[lkk + 1][lrow] = v0.y;
    Alds[lkk + 2][lrow] = v0.z;
    Alds[lkk + 3][lrow] = v0.w;
    Alds[lkk + 4][lrow] = v1.x;
    Alds[lkk + 5][lrow] = v1.y;
    Alds[lkk + 6][lrow] = v1.z;
    Alds[lkk + 7][lrow] = v1.w;
    __syncthreads();
#pragma unroll 4
    for (int k2 = 0; k2 < KB; ++k2) {
      float a0 = Alds[k2][ty * 4 + 0];
      float a1 = Alds[k2][ty * 4 + 1];
      float a2 = Alds[k2][ty * 4 + 2];
      float a3 = Alds[k2][ty * 4 + 3];
      const float* wp = W + (size_t)(kb + k2) * NOUT + tx * NC;
      float w[NC];
      if constexpr (NC % 4 == 0) {
#pragma unroll
        for (int j = 0; j < NC; j += 4) {
          float4 t = *(const float4*)(wp + j);
          w[j] = t.x; w[j + 1] = t.y; w[j + 2] = t.z; w[j + 3] = t.w;
        }
      } else {
        float2 t = *(const float2*)wp;
        w[0] = t.x; w[1] = t.y;
      }
#pragma unroll
      for (int j = 0; j < NC; ++j) {
        acc[0][j] = fmaf(a0, w[j], acc[0][j]);
        acc[1][j] = fmaf(a1, w[j], acc[1][j]);
        acc[2][j] = fmaf(a2, w[j], acc[2][j]);
        acc[3][j] = fmaf(a3, w[j], acc[3][j]);
      }
    }
    __syncthreads();
  }

#pragma unroll
  for (int i = 0; i < 4; ++i) {
    int grow2 = bm + ty * 4 + i;
    if (grow2 < M) {
      float* crow = C + (size_t)grow2 * NOUT + tx * NC;
#pragma unroll
      for (int j = 0; j < NC; ++j) {
        float v = acc[i][j];
        if constexpr (BIAS) v += bias[tx * NC + j];
        if constexpr (RELU) v = fmaxf(v, 0.f);
        crow[j] = v;
      }
    }
  }
}

// layer-1 gather: one wave per dst node; u[d] = [sum c0*h[s] | sum c1*h[s]]
__global__ __launch_bounds__(256) void gather1(
    const int* __restrict__ off, const int* __restrict__ degtot,
    const int* __restrict__ esrc, const float2* __restrict__ ecA,
    const float* __restrict__ h, float* __restrict__ u) {
  int wid = blockIdx.x * 4 + (threadIdx.x >> 6);
  int lane = threadIdx.x & 63;
  if (wid >= N) return;
  int start = off[wid];
  int cnt = degtot[wid];
  float2 u0 = make_float2(0.f, 0.f), u1 = make_float2(0.f, 0.f);
  if (cnt > 0) {
    int s = esrc[start];
    float2 c = ecA[start];
    for (int j = 1; j < cnt; ++j) {
      int sn = esrc[start + j];          // prefetch next edge header
      float2 cn = ecA[start + j];
      float2 hv = ((const float2*)(h + (size_t)s * H))[lane];
      u0.x = fmaf(c.x, hv.x, u0.x); u0.y = fmaf(c.x, hv.y, u0.y);
      u1.x = fmaf(c.y, hv.x, u1.x); u1.y = fmaf(c.y, hv.y, u1.y);
      s = sn; c = cn;
    }
    float2 hv = ((const float2*)(h + (size_t)s * H))[lane];
    u0.x = fmaf(c.x, hv.x, u0.x); u0.y = fmaf(c.x, hv.y, u0.y);
    u1.x = fmaf(c.y, hv.x, u1.x); u1.y = fmaf(c.y, hv.y, u1.y);
  }
  float* ur = u + (size_t)wid * 256;
  ((float2*)ur)[lane] = u0;
  ((float2*)(ur + 128))[lane] = u1;
}

// layer-2 gather: 16 lanes per node, writes d_out directly (bias folded in)
__global__ __launch_bounds__(256) void gather2(
    const int* __restrict__ off, const int* __restrict__ degtot,
    const int* __restrict__ esrc, const float2* __restrict__ ecB,
    const float* __restrict__ q, const float* __restrict__ bias2,
    float* __restrict__ out) {
  int node = blockIdx.x * 16 + (threadIdx.x >> 4);
  int k = threadIdx.x & 15;
  if (node >= N) return;
  int start = off[node];
  int cnt = degtot[node];
  float acc = bias2[k];
  for (int j = 0; j < cnt; ++j) {
    int s = esrc[start + j];
    float2 c = ecB[start + j];
    acc = fmaf(c.x, q[(size_t)s * 32 + k], acc);
    acc = fmaf(c.y, q[(size_t)s * 32 + 16 + k], acc);
  }
  out[(size_t)node * 16 + k] = acc;
}

}  // namespace

extern "C" void kernel_launch(void* const* d_in, const int* in_sizes, int n_in,
                              void* d_out, int out_size, void* d_ws, size_t ws_size,
                              hipStream_t stream) {
  const float* x       = (const float*)d_in[0];
  const int*   src     = (const int*)d_in[1];
  const int*   dst     = (const int*)d_in[2];
  const float* w_embed = (const float*)d_in[3];
  const float* b_embed = (const float*)d_in[4];
  const float* basis1  = (const float*)d_in[5];
  const float* coef1   = (const float*)d_in[6];
  const float* bias1   = (const float*)d_in[7];
  const float* basis2  = (const float*)d_in[8];
  const float* coef2   = (const float*)d_in[9];
  const float* bias2   = (const float*)d_in[10];
  float* out = (float*)d_out;

  float* ws = (float*)d_ws;
  float*  invdeg = ws;                          // R*N = 500,000 f
  float*  wc2    = invdeg + R * N;              // 128*32 = 4,096 f
  int*    degtot = (int*)(wc2 + 128 * 32);      // N
  int*    part   = degtot + N;                  // N (becomes off[])
  int*    bsum   = part + N;                    // 512
  int*    bscan  = bsum + 512;                  // 512
  int*    cursor = bscan + 512;                 // N
  int*    esrc   = cursor + N;                  // RE = 500,000
  float2* ecA    = (float2*)(esrc + RE);        // RE float2
  float2* ecB    = ecA + RE;                    // RE float2
  float*  h      = (float*)(ecB + RE);          // N*128
  float*  u      = h + (size_t)N * H;           // N*256
  float*  h2     = h;                           // alias: h dead after gather1
  float*  q      = u;                           // alias: u dead after GEMM2

  dim3 b256(256);
  hipMemsetAsync(invdeg, 0, (size_t)R * N * sizeof(float), stream);
  hipMemsetAsync(degtot, 0, (size_t)N * sizeof(int), stream);
  hipMemsetAsync(cursor, 0, (size_t)N * sizeof(int), stream);

  deg_count<<<(RE + 255) / 256, b256, 0, stream>>>(dst, invdeg, degtot);
  inv_deg_k<<<(R * N + 255) / 256, b256, 0, stream>>>(invdeg);
  scan_blk<<<NB, b256, 0, stream>>>(degtot, part, bsum, N);
  scan_top<<<1, dim3(512), 0, stream>>>(bsum, bscan, NB);
  scan_add<<<NB, b256, 0, stream>>>(part, bscan, N);
  fill_csr<<<(RE + 255) / 256, b256, 0, stream>>>(src, dst, coef1, coef2, invdeg,
                                                  part, cursor, esrc, ecA, ecB);
  build_wc<<<(128 * 32 + 255) / 256, b256, 0, stream>>>(basis2, wc2, 128, 16);

  int gblocks = (N + BM - 1) / BM;
  // h = x @ w_embed + b_embed
  gemm_f32<IN, 128, true, false><<<gblocks, b256, 0, stream>>>(x, w_embed, b_embed, h, N);
  // u[d] = [sum_e c0*h[src] | sum_e c1*h[src]]  (CSR gather, no atomics)
  gather1<<<(N + 3) / 4, b256, 0, stream>>>(part, degtot, esrc, ecA, h, u);
  // h2 = relu(u @ basis1_flat + bias1)   (basis1 flat IS the stacked [256,128])
  gemm_f32<256, 128, true, true><<<gblocks, b256, 0, stream>>>(u, basis1, bias1, h2, N);
  // q = h2 @ [V2_0 | V2_1]  -> [N, 32]
  gemm_f32<128, 32, false, false><<<gblocks, b256, 0, stream>>>(h2, wc2, nullptr, q, N);
  // out[d][k] = bias2[k] + sum_e (c0*q[s][k] + c1*q[s][16+k])
  gather2<<<(N + 15) / 16, b256, 0, stream>>>(part, degtot, esrc, ecB, q, bias2, out);
}

// Round 5
// 420.119 us; speedup vs baseline: 2.4942x; 1.4907x over previous
//
#include <hip/hip_runtime.h>
#include <hip/hip_bf16.h>
#include <cstddef>

namespace {

constexpr int N = 100000;
constexpr int IN = 256;
constexpr int H = 128;
constexpr int OUT = 16;
constexpr int R = 5;
constexpr int E = 100000;
constexpr int RE = R * E;
constexpr int NB = (N + 255) / 256;  // scan blocks

using short8 = __attribute__((ext_vector_type(8))) short;
using f32x4 = __attribute__((ext_vector_type(4))) float;

__device__ __forceinline__ float b2f(unsigned int u16) {
  union { unsigned int i; float f; } v;
  v.i = u16 << 16;
  return v.f;
}
__device__ __forceinline__ unsigned short f2b(float f) {
  union { float f; unsigned int u; } v;
  v.f = f;
  unsigned int r = v.u + 0x7fffu + ((v.u >> 16) & 1u);
  return (unsigned short)(r >> 16);
}

__global__ void deg_count(const int* __restrict__ dst, float* __restrict__ deg,
                          int* __restrict__ degtot) {
  int i = blockIdx.x * 256 + threadIdx.x;
  if (i < RE) {
    int d = dst[i];
    atomicAdd(&deg[(i / E) * N + d], 1.0f);
    atomicAdd(&degtot[d], 1);
  }
}

__global__ void inv_deg_k(float* __restrict__ deg) {
  int i = blockIdx.x * 256 + threadIdx.x;
  if (i < R * N) deg[i] = 1.0f / fmaxf(deg[i], 1.0f);
}

// ---- exclusive prefix scan over degtot ----
__global__ void scan_blk(const int* __restrict__ in, int* __restrict__ part,
                         int* __restrict__ bsum, int n) {
  __shared__ int tmp[256];
  int tid = threadIdx.x;
  int gid = blockIdx.x * 256 + tid;
  int v = (gid < n) ? in[gid] : 0;
  tmp[tid] = v;
  __syncthreads();
  for (int o = 1; o < 256; o <<= 1) {
    int t = (tid >= o) ? tmp[tid - o] : 0;
    __syncthreads();
    tmp[tid] += t;
    __syncthreads();
  }
  if (gid < n) part[gid] = tmp[tid] - v;
  if (tid == 255) bsum[blockIdx.x] = tmp[255];
}

__global__ void scan_top(const int* __restrict__ bsum, int* __restrict__ bscan, int nb) {
  __shared__ int tmp[512];
  int tid = threadIdx.x;
  int v = (tid < nb) ? bsum[tid] : 0;
  tmp[tid] = v;
  __syncthreads();
  for (int o = 1; o < 512; o <<= 1) {
    int t = (tid >= o) ? tmp[tid - o] : 0;
    __syncthreads();
    tmp[tid] += t;
    __syncthreads();
  }
  if (tid < nb) bscan[tid] = tmp[tid] - v;
}

__global__ void scan_add(int* __restrict__ part, const int* __restrict__ bscan, int n) {
  int gid = blockIdx.x * 256 + threadIdx.x;
  if (gid < n) part[gid] += bscan[gid >> 8];
}

__global__ void fill_csr(const int* __restrict__ src, const int* __restrict__ dst,
                         const float* __restrict__ coef1, const float* __restrict__ coef2,
                         const float* __restrict__ invdeg, const int* __restrict__ off,
                         int* __restrict__ cursor, int* __restrict__ esrc,
                         float2* __restrict__ ecA, float2* __restrict__ ecB) {
  int i = blockIdx.x * 256 + threadIdx.x;
  if (i >= RE) return;
  int r = i / E;
  int d = dst[i];
  int slot = off[d] + atomicAdd(&cursor[d], 1);
  float id = invdeg[r * N + d];
  esrc[slot] = src[i];
  ecA[slot] = make_float2(coef1[2 * r] * id, coef1[2 * r + 1] * id);
  ecB[slot] = make_float2(coef2[2 * r] * id, coef2[2 * r + 1] * id);
}

// pack W[K][NOUT] fp32 -> bf16 MFMA B-fragment order:
// wp[((kc*NCT+ct)*64 + lane)*8 + ii] = W[kc*32 + (lane>>4)*8 + ii][ct*16 + (lane&15)]
__global__ void pack_w(const float* __restrict__ W, unsigned short* __restrict__ wp,
                       int NOUT, int total) {
  int i = blockIdx.x * 256 + threadIdx.x;
  if (i >= total) return;
  int ii = i & 7;
  int lane = (i >> 3) & 63;
  int fb = i >> 9;
  int NCT = NOUT >> 4;
  int kc = fb / NCT, ct = fb - kc * NCT;
  int k = kc * 32 + ((lane >> 4) << 3) + ii;
  int col = (ct << 4) + (lane & 15);
  wp[i] = f2b(W[(size_t)k * NOUT + col]);
}

// pack basis2[2][128][16] as the [128][32] matrix (cols = [b0:16 | b1:16])
__global__ void pack_b2(const float* __restrict__ basis2, unsigned short* __restrict__ wp) {
  int i = blockIdx.x * 256 + threadIdx.x;
  if (i >= 128 * 32) return;
  int ii = i & 7;
  int lane = (i >> 3) & 63;
  int fb = i >> 9;            // NCT = 2
  int kc = fb >> 1, ct = fb & 1;
  int k = kc * 32 + ((lane >> 4) << 3) + ii;
  wp[i] = f2b(basis2[((size_t)ct * 128 + k) * 16 + (lane & 15)]);
}

// C[M,NOUT](bf16) = A[M,K] @ Wpack + bias (+relu). A fp32 or bf16.
// 256 thr = 4 waves, BM=64 (16 rows/wave), MFMA 16x16x32 bf16.
template <int K, int NOUT, bool AF32, bool BIAS, bool RELU>
__global__ __launch_bounds__(256) void gemm_mfma(
    const void* __restrict__ Araw, const unsigned short* __restrict__ wpack,
    const float* __restrict__ bias, unsigned short* __restrict__ C, int M) {
  constexpr int KC = K / 32;
  constexpr int NCT = NOUT / 16;
  __shared__ __align__(16) unsigned short alds[64][40];  // pad 32->40: <=2-way banks
  const int tid = threadIdx.x;
  const int wv = tid >> 6;
  const int lane = tid & 63;
  const int bm = blockIdx.x * 64;

  f32x4 acc[NCT];
#pragma unroll
  for (int t = 0; t < NCT; ++t) acc[t] = (f32x4){0.f, 0.f, 0.f, 0.f};

  const int srow = tid >> 2;          // 64 rows staged by 256 threads
  const int skk = (tid & 3) * 8;      // 8 bf16 each
  int grow = bm + srow;
  if (grow > M - 1) grow = M - 1;

  const short8* wfrag = (const short8*)wpack;

  for (int kc = 0; kc < KC; ++kc) {
    if constexpr (AF32) {
      const float* ap = (const float*)Araw + (size_t)grow * K + kc * 32 + skk;
      float4 v0 = *(const float4*)ap;
      float4 v1 = *(const float4*)(ap + 4);
      short8 pk;
      pk[0] = (short)f2b(v0.x); pk[1] = (short)f2b(v0.y);
      pk[2] = (short)f2b(v0.z); pk[3] = (short)f2b(v0.w);
      pk[4] = (short)f2b(v1.x); pk[5] = (short)f2b(v1.y);
      pk[6] = (short)f2b(v1.z); pk[7] = (short)f2b(v1.w);
      *(short8*)&alds[srow][skk] = pk;
    } else {
      const unsigned short* ap = (const unsigned short*)Araw + (size_t)grow * K + kc * 32 + skk;
      *(short8*)&alds[srow][skk] = *(const short8*)ap;
    }
    __syncthreads();
    // A-frag: row = lane&15 (within wave tile), k = (lane>>4)*8 + i
    short8 af = *(const short8*)&alds[wv * 16 + (lane & 15)][(lane >> 4) * 8];
#pragma unroll
    for (int ct = 0; ct < NCT; ++ct) {
      short8 bf = wfrag[(kc * NCT + ct) * 64 + lane];
      acc[ct] = __builtin_amdgcn_mfma_f32_16x16x32_bf16(af, bf, acc[ct], 0, 0, 0);
    }
    __syncthreads();
  }

  // D: col = ct*16 + (lane&15), row = wv*16 + (lane>>4)*4 + i
  const int c16 = lane & 15;
  const int rg = lane >> 4;
#pragma unroll
  for (int ct = 0; ct < NCT; ++ct) {
    int col = ct * 16 + c16;
    float bs = 0.f;
    if constexpr (BIAS) bs = bias[col];
#pragma unroll
    for (int i = 0; i < 4; ++i) {
      int row = bm + wv * 16 + rg * 4 + i;
      if (row < M) {
        float v = acc[ct][i] + bs;
        if constexpr (RELU) v = fmaxf(v, 0.f);
        C[(size_t)row * NOUT + col] = f2b(v);
      }
    }
  }
}

// layer-1 gather (CSR): one wave per dst node, h bf16 rows (256 B coalesced)
__global__ __launch_bounds__(256) void gather1(
    const int* __restrict__ off, const int* __restrict__ degtot,
    const int* __restrict__ esrc, const float2* __restrict__ ecA,
    const unsigned short* __restrict__ hbf, unsigned int* __restrict__ ubf) {
  int wid = blockIdx.x * 4 + (threadIdx.x >> 6);
  int lane = threadIdx.x & 63;
  if (wid >= N) return;
  int start = off[wid];
  int cnt = degtot[wid];
  float u0x = 0.f, u0y = 0.f, u1x = 0.f, u1y = 0.f;
  if (cnt > 0) {
    int s = esrc[start];
    float2 c = ecA[start];
    unsigned int hv = ((const unsigned int*)(hbf + (size_t)s * 128))[lane];
    for (int j = 1; j < cnt; ++j) {
      int sn = esrc[start + j];
      float2 cn = ecA[start + j];
      unsigned int hvn = ((const unsigned int*)(hbf + (size_t)sn * 128))[lane];
      float hx = b2f(hv & 0xffffu), hy = b2f(hv >> 16);
      u0x = fmaf(c.x, hx, u0x); u0y = fmaf(c.x, hy, u0y);
      u1x = fmaf(c.y, hx, u1x); u1y = fmaf(c.y, hy, u1y);
      s = sn; c = cn; hv = hvn;
    }
    float hx = b2f(hv & 0xffffu), hy = b2f(hv >> 16);
    u0x = fmaf(c.x, hx, u0x); u0y = fmaf(c.x, hy, u0y);
    u1x = fmaf(c.y, hx, u1x); u1y = fmaf(c.y, hy, u1y);
  }
  unsigned int* ur = ubf + (size_t)wid * 128;  // 256 bf16 = 128 dwords
  ur[lane]      = (unsigned int)f2b(u0x) | ((unsigned int)f2b(u0y) << 16);
  ur[64 + lane] = (unsigned int)f2b(u1x) | ((unsigned int)f2b(u1y) << 16);
}

// layer-2 gather: 16 lanes per node, q bf16, writes fp32 d_out (bias folded)
__global__ __launch_bounds__(256) void gather2(
    const int* __restrict__ off, const int* __restrict__ degtot,
    const int* __restrict__ esrc, const float2* __restrict__ ecB,
    const unsigned short* __restrict__ qbf, const float* __restrict__ bias2,
    float* __restrict__ out) {
  int node = blockIdx.x * 16 + (threadIdx.x >> 4);
  int k = threadIdx.x & 15;
  if (node >= N) return;
  int start = off[node];
  int cnt = degtot[node];
  float acc = bias2[k];
  for (int j = 0; j < cnt; ++j) {
    int s = esrc[start + j];
    float2 c = ecB[start + j];
    acc = fmaf(c.x, b2f(qbf[(size_t)s * 32 + k]), acc);
    acc = fmaf(c.y, b2f(qbf[(size_t)s * 32 + 16 + k]), acc);
  }
  out[(size_t)node * 16 + k] = acc;
}

}  // namespace

extern "C" void kernel_launch(void* const* d_in, const int* in_sizes, int n_in,
                              void* d_out, int out_size, void* d_ws, size_t ws_size,
                              hipStream_t stream) {
  const float* x       = (const float*)d_in[0];
  const int*   src     = (const int*)d_in[1];
  const int*   dst     = (const int*)d_in[2];
  const float* w_embed = (const float*)d_in[3];
  const float* b_embed = (const float*)d_in[4];
  const float* basis1  = (const float*)d_in[5];
  const float* coef1   = (const float*)d_in[6];
  const float* bias1   = (const float*)d_in[7];
  const float* basis2  = (const float*)d_in[8];
  const float* coef2   = (const float*)d_in[9];
  const float* bias2   = (const float*)d_in[10];
  float* out = (float*)d_out;

  // ws layout (16B-aligned sections)
  float2* ecA = (float2*)d_ws;                         // RE
  float2* ecB = ecA + RE;                              // RE
  float*  invdeg = (float*)(ecB + RE);                 // R*N
  int*    degtot = (int*)(invdeg + (size_t)R * N);     // N
  int*    off    = degtot + N;                         // N
  int*    bsum   = off + N;                            // 512
  int*    bscan  = bsum + 512;                         // 512
  int*    cursor = bscan + 512;                        // N
  int*    esrc   = cursor + N;                         // RE
  unsigned short* wp1  = (unsigned short*)(esrc + RE); // 256*128
  unsigned short* wpB1 = wp1 + 256 * 128;              // 256*128
  unsigned short* wpB2 = wpB1 + 256 * 128;             // 128*32
  unsigned short* h_bf = wpB2 + 128 * 32;              // N*128
  unsigned short* u_bf = h_bf + (size_t)N * 128;       // N*256
  unsigned short* h2_bf = h_bf;                        // alias: h dead after gather1
  unsigned short* q_bf  = u_bf;                        // alias: u dead after GEMM2

  dim3 b256(256);
  hipMemsetAsync(invdeg, 0, (size_t)R * N * sizeof(float), stream);
  hipMemsetAsync(degtot, 0, (size_t)N * sizeof(int), stream);
  hipMemsetAsync(cursor, 0, (size_t)N * sizeof(int), stream);

  deg_count<<<(RE + 255) / 256, b256, 0, stream>>>(dst, invdeg, degtot);
  inv_deg_k<<<(R * N + 255) / 256, b256, 0, stream>>>(invdeg);
  scan_blk<<<NB, b256, 0, stream>>>(degtot, off, bsum, N);
  scan_top<<<1, dim3(512), 0, stream>>>(bsum, bscan, NB);
  scan_add<<<NB, b256, 0, stream>>>(off, bscan, N);
  fill_csr<<<(RE + 255) / 256, b256, 0, stream>>>(src, dst, coef1, coef2, invdeg,
                                                  off, cursor, esrc, ecA, ecB);
  pack_w<<<(256 * 128 + 255) / 256, b256, 0, stream>>>(w_embed, wp1, 128, 256 * 128);
  pack_w<<<(256 * 128 + 255) / 256, b256, 0, stream>>>(basis1, wpB1, 128, 256 * 128);
  pack_b2<<<(128 * 32 + 255) / 256, b256, 0, stream>>>(basis2, wpB2);

  int gblocks = (N + 63) / 64;
  // h = x @ w_embed + b_embed          (A fp32 -> bf16 on the fly)
  gemm_mfma<256, 128, true, true, false>
      <<<gblocks, b256, 0, stream>>>(x, wp1, b_embed, h_bf, N);
  // u[d] = [sum c0*h[s] | sum c1*h[s]]  (CSR gather, bf16 rows)
  gather1<<<(N + 3) / 4, b256, 0, stream>>>(off, degtot, esrc, ecA, h_bf,
                                            (unsigned int*)u_bf);
  // h2 = relu(u @ basis1 + bias1)
  gemm_mfma<256, 128, false, true, true>
      <<<gblocks, b256, 0, stream>>>(u_bf, wpB1, bias1, h2_bf, N);
  // q = h2 @ [V2_0 | V2_1]
  gemm_mfma<128, 32, false, false, false>
      <<<gblocks, b256, 0, stream>>>(h2_bf, wpB2, nullptr, q_bf, N);
  // out[d][k] = bias2[k] + sum (c0*q[s][k] + c1*q[s][16+k])
  gather2<<<(N + 15) / 16, b256, 0, stream>>>(off, degtot, esrc, ecB, q_bf, bias2, out);
}